// Round 9
// baseline (226.188 us; speedup 1.0000x reference)
//
#include <hip/hip_runtime.h>

// B=2, S=2048, D=1024, H=16, DH=64. fp32 in/out, f16 MFMA internally.
// ws: Wcat(6M)@8M Wot(2M)@14M Q(8M)@16M K(8M)@24M Vt(8M)@32M ctx(8M)@40M

typedef _Float16 f16;
typedef _Float16 f16x8 __attribute__((ext_vector_type(8)));
typedef _Float16 f16x4 __attribute__((ext_vector_type(4)));
typedef float    f32x4 __attribute__((ext_vector_type(4)));

__device__ __forceinline__ void gload16(const void* g, void* l) {
  __builtin_amdgcn_global_load_lds(
      (const __attribute__((address_space(1))) void*)g,
      (__attribute__((address_space(3))) void*)l, 16, 0, 0);
}

// ---------------- weight convert+transpose ----------------
__global__ void cvt_w(const float* __restrict__ W0, const float* __restrict__ W1,
                      const float* __restrict__ W2, const float* __restrict__ W3,
                      f16* __restrict__ T0, f16* __restrict__ T1,
                      f16* __restrict__ T2, f16* __restrict__ T3) {
  const float* W = blockIdx.z == 0 ? W0 : blockIdx.z == 1 ? W1 : blockIdx.z == 2 ? W2 : W3;
  f16*        Tt = blockIdx.z == 0 ? T0 : blockIdx.z == 1 ? T1 : blockIdx.z == 2 ? T2 : T3;
  __shared__ f16 tile[64][65];
  int tid = threadIdx.x;
  int k0 = blockIdx.y * 64, n0 = blockIdx.x * 64;
  int rr = tid >> 4, cc = (tid & 15) * 4;
#pragma unroll
  for (int p = 0; p < 4; ++p) {
    int r = rr + p * 16;
    float4 v = *(const float4*)(W + (size_t)(k0 + r) * 1024 + n0 + cc);
    tile[r][cc + 0] = (f16)v.x; tile[r][cc + 1] = (f16)v.y;
    tile[r][cc + 2] = (f16)v.z; tile[r][cc + 3] = (f16)v.w;
  }
  __syncthreads();
#pragma unroll
  for (int p = 0; p < 4; ++p) {
    int r = rr + p * 16;
    f16x4 v;
#pragma unroll
    for (int j = 0; j < 4; ++j) v[j] = tile[cc + j][r];
    *(f16x4*)(Tt + (size_t)(n0 + r) * 1024 + k0 + cc) = v;
  }
}

// ---------------- GEMM ----------------
// MODE 0: fused QKV, A = fp32 x (converted in-staging). Bt = Wcat[3072][1024].
//         seg 0->Q f16 [bh][s][dh], 1->K, 2->V^T f16 [bh][dh][s].
// MODE 3: out-proj split-K (blockIdx.z halves of K), A = f16 ctx.
//         Epilogue: atomicAdd fp32 into oO (pre-zeroed); split 0 adds bias.
template <int MODE>
__global__ __launch_bounds__(256, 2)
void gemm_k(const float* __restrict__ Af32, const f16* __restrict__ Af16,
            const f16* __restrict__ Bt,
            f16* __restrict__ oQ, f16* __restrict__ oK, f16* __restrict__ oV,
            float* __restrict__ oO, const float* __restrict__ bias) {
  constexpr int Kd = 1024;
  __shared__ f16 smem[2 * 128 * 64];
  f16* sA = smem;
  f16* sB = smem + 128 * 64;
  const int tid = threadIdx.x;
  const int lane = tid & 63, wid = tid >> 6;
  const int wr = wid >> 1, wc = wid & 1;
  const int bm = blockIdx.y * 128, bn = blockIdx.x * 128;
  const int kbeg = (MODE == 3) ? blockIdx.z * 512 : 0;
  const int kend = (MODE == 3) ? kbeg + 512 : Kd;

  f32x4 acc[4][4] = {};

  for (int k0 = kbeg; k0 < kend; k0 += 64) {
#pragma unroll
    for (int p = 0; p < 4; ++p) {
      int c = p * 256 + tid;
      int row = c >> 3;
      int gc = (c & 7) ^ (row & 7);
      if constexpr (MODE == 0) {
        const float* src = Af32 + (size_t)(bm + row) * Kd + k0 + gc * 8;
        float4 u0 = *(const float4*)(src);
        float4 u1 = *(const float4*)(src + 4);
        f16x8 w = { (f16)u0.x, (f16)u0.y, (f16)u0.z, (f16)u0.w,
                    (f16)u1.x, (f16)u1.y, (f16)u1.z, (f16)u1.w };
        *(f16x8*)(sA + c * 8) = w;
      } else {
        gload16(Af16 + (size_t)(bm + row) * Kd + k0 + gc * 8, sA + c * 8);
      }
      gload16(Bt + (size_t)(bn + row) * Kd + k0 + gc * 8, sB + c * 8);
    }
    __syncthreads();
#pragma unroll
    for (int ks = 0; ks < 2; ++ks) {
      f16x8 af[4], bf[4];
#pragma unroll
      for (int m = 0; m < 4; ++m) {
        int row = wr * 64 + m * 16 + (lane & 15);
        int j = (ks * 4 + (lane >> 4)) ^ (row & 7);
        af[m] = *(const f16x8*)((const char*)sA + row * 128 + j * 16);
      }
#pragma unroll
      for (int n = 0; n < 4; ++n) {
        int row = wc * 64 + n * 16 + (lane & 15);
        int j = (ks * 4 + (lane >> 4)) ^ (row & 7);
        bf[n] = *(const f16x8*)((const char*)sB + row * 128 + j * 16);
      }
#pragma unroll
      for (int m = 0; m < 4; ++m)
#pragma unroll
        for (int n = 0; n < 4; ++n)
          acc[m][n] = __builtin_amdgcn_mfma_f32_16x16x32_f16(af[m], bf[n], acc[m][n], 0, 0, 0);
    }
    __syncthreads();
  }

  if constexpr (MODE == 3) {
    const bool addb = (blockIdx.z == 0);
#pragma unroll
    for (int m = 0; m < 4; ++m) {
      int rbase = bm + wr * 64 + m * 16 + ((lane >> 4) << 2);
#pragma unroll
      for (int n = 0; n < 4; ++n) {
        int ncol = bn + wc * 64 + n * 16 + (lane & 15);
        float bv = addb ? bias[ncol] : 0.f;
#pragma unroll
        for (int i = 0; i < 4; ++i)
          atomicAdd(&oO[(size_t)(rbase + i) * 1024 + ncol], acc[m][n][i] + bv);
      }
    }
  } else {
    const int seg = bn >> 10;
    if (seg < 2) {
      f16* dst = seg == 0 ? oQ : oK;
#pragma unroll
      for (int m = 0; m < 4; ++m) {
        int rbase = bm + wr * 64 + m * 16 + ((lane >> 4) << 2);
#pragma unroll
        for (int n = 0; n < 4; ++n) {
          int ncol = (bn & 1023) + wc * 64 + n * 16 + (lane & 15);
          int h = ncol >> 6, dh = ncol & 63;
#pragma unroll
          for (int i = 0; i < 4; ++i) {
            int rr = rbase + i;
            int b = rr >> 11, s = rr & 2047;
            dst[(((size_t)(b * 16 + h) * 2048 + s) << 6) + dh] = (f16)acc[m][n][i];
          }
        }
      }
    } else {
      f16* T64 = smem;                   // [64][132]
      int b = bm >> 11, sbase = bm & 2047;
      int bnl = bn & 1023;
#pragma unroll
      for (int p = 0; p < 2; ++p) {
        if (wr == p) {
#pragma unroll
          for (int m = 0; m < 4; ++m)
#pragma unroll
            for (int n = 0; n < 4; ++n)
#pragma unroll
              for (int i = 0; i < 4; ++i) {
                int rl = m * 16 + ((lane >> 4) << 2) + i;
                int col = wc * 64 + n * 16 + (lane & 15);
                T64[rl * 132 + col] = (f16)acc[m][n][i];
              }
        }
        __syncthreads();
#pragma unroll
        for (int it = 0; it < 4; ++it) {
          int oc = it * 256 + tid;
          int ocol = oc >> 3;
          int och = oc & 7;
          f16x8 v;
#pragma unroll
          for (int j = 0; j < 8; ++j) v[j] = T64[(och * 8 + j) * 132 + ocol];
          int ncol = bnl + ocol;
          int h = ncol >> 6, dh = ncol & 63;
          *(f16x8*)(oV + ((size_t)((b * 16 + h) * 64 + dh) << 11) + sbase + p * 64 + och * 8) = v;
        }
        __syncthreads();
      }
    }
  }
}

// ---------------- causal flash attention (R7-verified, 65 us) ----------------
// grid (pair=16, bh=32), 4 waves. Block handles q-tiles {bx, 31-bx} -> uniform
// 33 KV iterations. Swapped QK^T (mfma(K,Q) -> S^T): q-row = lane&15 is
// lane-local -> softmax reduce = local 16-max/sum + 2 shfl_xor.
__global__ __launch_bounds__(256, 2)
void attn_k(const f16* __restrict__ Q, const f16* __restrict__ Kg,
            const f16* __restrict__ Vt, f16* __restrict__ ctx) {
  __shared__ f16 sK[64 * 64];
  __shared__ f16 sV[64 * 64];
  __shared__ f16 sP[4][16 * 64];
  const int tid = threadIdx.x, lane = tid & 63, wid = tid >> 6;
  const int bh = blockIdx.y;
  const int b = bh >> 4, h = bh & 15;
  const f16* Qb = Q + ((size_t)bh << 17);
  const f16* Kb = Kg + ((size_t)bh << 17);
  const f16* Vb = Vt + ((size_t)bh << 17);
  const float SC = 0.1803368801f;            // 0.125 * log2(e)

  for (int half = 0; half < 2; ++half) {
    const int qt = half == 0 ? blockIdx.x : 31 - blockIdx.x;
    const int qbase = qt * 64 + wid * 16;
    const int qg = qbase + (lane & 15);
    const int qmax_w = qbase + 15;

    const int qrow_a = qbase + (lane & 15);
    f16x8 qf[2];
    qf[0] = *(const f16x8*)(Qb + (size_t)qrow_a * 64 + ((lane >> 4) << 3));
    qf[1] = *(const f16x8*)(Qb + (size_t)qrow_a * 64 + 32 + ((lane >> 4) << 3));

    f32x4 acc[4] = {};
    float m_run = -INFINITY, l_run = 0.f;

    for (int kt = 0; kt <= qt; ++kt) {
#pragma unroll
      for (int p = 0; p < 2; ++p) {
        int c = p * 256 + tid;
        int row = c >> 3;
        int gc = (c & 7) ^ (row & 7);
        gload16(Kb + (size_t)(kt * 64 + row) * 64 + gc * 8, sK + c * 8);
        gload16(Vb + (size_t)row * 2048 + kt * 64 + gc * 8, sV + c * 8);
      }
      __syncthreads();

      // S^T = K Q^T : mfma(A=K_frag, B=Q_frag). Output: row=k_local, col=q.
      f32x4 sf[4];
#pragma unroll
      for (int kc = 0; kc < 4; ++kc) {
        if (kt * 64 + kc * 16 <= qmax_w) {
          f32x4 z = {};
#pragma unroll
          for (int ks = 0; ks < 2; ++ks) {
            int row = kc * 16 + (lane & 15);
            int j = (ks * 4 + (lane >> 4)) ^ (row & 7);
            f16x8 kf = *(const f16x8*)((const char*)sK + row * 128 + j * 16);
            z = __builtin_amdgcn_mfma_f32_16x16x32_f16(kf, qf[ks], z, 0, 0, 0);
          }
          sf[kc] = z;
        } else {
          sf[kc] = (f32x4){-1e30f, -1e30f, -1e30f, -1e30f};
        }
      }
#pragma unroll
      for (int kc = 0; kc < 4; ++kc) {
        if (kt * 64 + kc * 16 + 15 > qbase) {
#pragma unroll
          for (int i = 0; i < 4; ++i) {
            int kg = kt * 64 + kc * 16 + ((lane >> 4) << 2) + i;
            sf[kc][i] = (kg <= qg) ? sf[kc][i] * SC : -1e30f;
          }
        } else {
#pragma unroll
          for (int i = 0; i < 4; ++i) sf[kc][i] *= SC;
        }
      }
      float v01 = fmaxf(fmaxf(sf[0][0], sf[0][1]), fmaxf(sf[0][2], sf[0][3]));
      float v23 = fmaxf(fmaxf(sf[1][0], sf[1][1]), fmaxf(sf[1][2], sf[1][3]));
      float v45 = fmaxf(fmaxf(sf[2][0], sf[2][1]), fmaxf(sf[2][2], sf[2][3]));
      float v67 = fmaxf(fmaxf(sf[3][0], sf[3][1]), fmaxf(sf[3][2], sf[3][3]));
      float v = fmaxf(fmaxf(v01, v23), fmaxf(v45, v67));
      v = fmaxf(v, __shfl_xor(v, 16));
      v = fmaxf(v, __shfl_xor(v, 32));
      float mn = fmaxf(m_run, v);
      float scl = __builtin_amdgcn_exp2f(m_run - mn);
      m_run = mn;
      float ls = 0.f;
#pragma unroll
      for (int kc = 0; kc < 4; ++kc)
#pragma unroll
        for (int i = 0; i < 4; ++i) {
          float p = __builtin_amdgcn_exp2f(sf[kc][i] - mn);
          sf[kc][i] = p;
          ls += p;
        }
      ls += __shfl_xor(ls, 16);
      ls += __shfl_xor(ls, 32);
      l_run = l_run * scl + ls;
#pragma unroll
      for (int i = 0; i < 4; ++i) {
        float sb = __shfl(scl, ((lane >> 4) << 2) + i);
#pragma unroll
        for (int d = 0; d < 4; ++d) acc[d][i] *= sb;
      }
      char* Pw = (char*)(sP[wid]);
#pragma unroll
      for (int kc = 0; kc < 4; ++kc) {
        int kbase = kc * 16 + ((lane >> 4) << 2);
        int ch = kbase >> 3;
        f16x4 pv = { (f16)sf[kc][0], (f16)sf[kc][1], (f16)sf[kc][2], (f16)sf[kc][3] };
        *(f16x4*)(Pw + (lane & 15) * 128 + ((ch ^ (lane & 7)) << 4) + ((kbase & 7) << 1)) = pv;
      }
#pragma unroll
      for (int kk = 0; kk < 2; ++kk) {
        if (kt * 64 + kk * 32 <= qmax_w) {
          int prow = lane & 15;
          int pj = (kk * 4 + (lane >> 4)) ^ (prow & 7);
          f16x8 pa = *(const f16x8*)(Pw + prow * 128 + pj * 16);
#pragma unroll
          for (int d = 0; d < 4; ++d) {
            int vrow = d * 16 + (lane & 15);
            int vj = (kk * 4 + (lane >> 4)) ^ (vrow & 7);
            f16x8 vf = *(const f16x8*)((const char*)sV + vrow * 128 + vj * 16);
            acc[d] = __builtin_amdgcn_mfma_f32_16x16x32_f16(pa, vf, acc[d], 0, 0, 0);
          }
        }
      }
      __syncthreads();
    }
#pragma unroll
    for (int i = 0; i < 4; ++i) {
      float lb = __shfl(l_run, ((lane >> 4) << 2) + i);
      float r = 1.f / lb;
      int s = qbase + ((lane >> 4) << 2) + i;
#pragma unroll
      for (int d = 0; d < 4; ++d) {
        float val = acc[d][i] * r;
        ctx[((size_t)(b * 2048 + s) << 10) + (h << 6) + (d << 4) + (lane & 15)] = (f16)val;
      }
    }
  }
}

extern "C" void kernel_launch(void* const* d_in, const int* in_sizes, int n_in,
                              void* d_out, int out_size, void* d_ws, size_t ws_size,
                              hipStream_t stream) {
  const float* x  = (const float*)d_in[0];
  const float* Wq = (const float*)d_in[1];
  const float* Wk = (const float*)d_in[2];
  const float* Wv = (const float*)d_in[3];
  const float* Wo = (const float*)d_in[4];
  const float* bo = (const float*)d_in[5];
  char* ws = (char*)d_ws;
  f16* Wcat = (f16*)(ws + ((size_t)8  << 20));
  f16* Wot  = (f16*)(ws + ((size_t)14 << 20));
  f16* Qb   = (f16*)(ws + ((size_t)16 << 20));
  f16* Kb   = (f16*)(ws + ((size_t)24 << 20));
  f16* Vtb  = (f16*)(ws + ((size_t)32 << 20));
  f16* ctx  = (f16*)(ws + ((size_t)40 << 20));
  const size_t MM = (size_t)1024 * 1024;

  // zero d_out for split-K atomic accumulation (stream-ordered, capture-safe)
  hipMemsetAsync(d_out, 0, (size_t)out_size * sizeof(float), stream);
  hipLaunchKernelGGL(cvt_w, dim3(16, 16, 4), dim3(256), 0, stream,
                     Wq, Wk, Wv, Wo, Wcat, Wcat + MM, Wcat + 2 * MM, Wot);
  hipLaunchKernelGGL((gemm_k<0>), dim3(24, 32), dim3(256), 0, stream,
                     x, nullptr, Wcat, Qb, Kb, Vtb, nullptr, nullptr);
  hipLaunchKernelGGL(attn_k, dim3(16, 32), dim3(256), 0, stream, Qb, Kb, Vtb, ctx);
  hipLaunchKernelGGL((gemm_k<3>), dim3(8, 32, 2), dim3(256), 0, stream,
                     nullptr, ctx, Wot, nullptr, nullptr, nullptr, (float*)d_out, bo);
}

// Round 10
// 188.220 us; speedup vs baseline: 1.2017x; 1.2017x over previous
//
#include <hip/hip_runtime.h>

// B=2, S=2048, D=1024, H=16, DH=64. fp32 in/out, f16 MFMA internally.
// ws: xb(8M) Wcat(6M)@8M Wot(2M)@14M Q(8M)@16M K(8M)@24M Vt(8M)@32M ctx(8M)@40M

typedef _Float16 f16;
typedef _Float16 f16x8 __attribute__((ext_vector_type(8)));
typedef _Float16 f16x4 __attribute__((ext_vector_type(4)));
typedef float    f32x4 __attribute__((ext_vector_type(4)));

__device__ __forceinline__ void gload16(const void* g, void* l) {
  __builtin_amdgcn_global_load_lds(
      (const __attribute__((address_space(1))) void*)g,
      (__attribute__((address_space(3))) void*)l, 16, 0, 0);
}

// ---------------- converts ----------------
__global__ void cvt_x(const float* __restrict__ x, f16* __restrict__ xb) {
  int idx = blockIdx.x * 256 + threadIdx.x;
  float4 v = ((const float4*)x)[idx];
  f16x4 o = { (f16)v.x, (f16)v.y, (f16)v.z, (f16)v.w };
  ((f16x4*)xb)[idx] = o;
}

__global__ void cvt_w(const float* __restrict__ W0, const float* __restrict__ W1,
                      const float* __restrict__ W2, const float* __restrict__ W3,
                      f16* __restrict__ T0, f16* __restrict__ T1,
                      f16* __restrict__ T2, f16* __restrict__ T3) {
  const float* W = blockIdx.z == 0 ? W0 : blockIdx.z == 1 ? W1 : blockIdx.z == 2 ? W2 : W3;
  f16*        Tt = blockIdx.z == 0 ? T0 : blockIdx.z == 1 ? T1 : blockIdx.z == 2 ? T2 : T3;
  __shared__ f16 tile[64][65];
  int tid = threadIdx.x;
  int k0 = blockIdx.y * 64, n0 = blockIdx.x * 64;
  int rr = tid >> 4, cc = (tid & 15) * 4;
#pragma unroll
  for (int p = 0; p < 4; ++p) {
    int r = rr + p * 16;
    float4 v = *(const float4*)(W + (size_t)(k0 + r) * 1024 + n0 + cc);
    tile[r][cc + 0] = (f16)v.x; tile[r][cc + 1] = (f16)v.y;
    tile[r][cc + 2] = (f16)v.z; tile[r][cc + 3] = (f16)v.w;
  }
  __syncthreads();
#pragma unroll
  for (int p = 0; p < 4; ++p) {
    int r = rr + p * 16;
    f16x4 v;
#pragma unroll
    for (int j = 0; j < 4; ++j) v[j] = tile[cc + j][r];
    *(f16x4*)(Tt + (size_t)(n0 + r) * 1024 + k0 + cc) = v;
  }
}

// ---------------- GEMM ----------------
// MODE 0: fused QKV, 128x128 tile. Bt=Wcat[3072][1024]; seg 0->Q, 1->K, 2->V^T.
// MODE 2: out-proj, 128x64 tile (grid 512 = 2 blocks/CU), fp32 + bias.
template <int MODE>
__global__ __launch_bounds__(256, 2)
void gemm_k(const f16* __restrict__ A, const f16* __restrict__ Bt,
            f16* __restrict__ oQ, f16* __restrict__ oK, f16* __restrict__ oV,
            float* __restrict__ oO, const float* __restrict__ bias) {
  constexpr int Kd = 1024;
  constexpr int BN = (MODE == 2) ? 64 : 128;   // N-tile
  constexpr int NF = BN / 32;                  // n fragments per wave
  __shared__ f16 smem[128 * 64 + BN * 64];
  f16* sA = smem;
  f16* sB = smem + 128 * 64;
  const int tid = threadIdx.x;
  const int lane = tid & 63, wid = tid >> 6;
  const int wr = wid >> 1, wc = wid & 1;
  const int bm = blockIdx.y * 128, bn = blockIdx.x * BN;

  f32x4 acc[4][NF] = {};

  for (int k0 = 0; k0 < Kd; k0 += 64) {
#pragma unroll
    for (int p = 0; p < 4; ++p) {
      int c = p * 256 + tid;
      int row = c >> 3;
      int gc = (c & 7) ^ (row & 7);
      gload16(A + (size_t)(bm + row) * Kd + k0 + gc * 8, sA + c * 8);
    }
#pragma unroll
    for (int p = 0; p < NF; ++p) {
      int c = p * 256 + tid;
      int row = c >> 3;
      int gc = (c & 7) ^ (row & 7);
      gload16(Bt + (size_t)(bn + row) * Kd + k0 + gc * 8, sB + c * 8);
    }
    __syncthreads();
#pragma unroll
    for (int ks = 0; ks < 2; ++ks) {
      f16x8 af[4], bf[NF];
#pragma unroll
      for (int m = 0; m < 4; ++m) {
        int row = wr * 64 + m * 16 + (lane & 15);
        int j = (ks * 4 + (lane >> 4)) ^ (row & 7);
        af[m] = *(const f16x8*)((const char*)sA + row * 128 + j * 16);
      }
#pragma unroll
      for (int n = 0; n < NF; ++n) {
        int row = wc * (BN / 2) + n * 16 + (lane & 15);
        int j = (ks * 4 + (lane >> 4)) ^ (row & 7);
        bf[n] = *(const f16x8*)((const char*)sB + row * 128 + j * 16);
      }
#pragma unroll
      for (int m = 0; m < 4; ++m)
#pragma unroll
        for (int n = 0; n < NF; ++n)
          acc[m][n] = __builtin_amdgcn_mfma_f32_16x16x32_f16(af[m], bf[n], acc[m][n], 0, 0, 0);
    }
    __syncthreads();
  }

  if constexpr (MODE == 2) {
#pragma unroll
    for (int m = 0; m < 4; ++m) {
      int rbase = bm + wr * 64 + m * 16 + ((lane >> 4) << 2);
#pragma unroll
      for (int n = 0; n < NF; ++n) {
        int ncol = bn + wc * (BN / 2) + n * 16 + (lane & 15);
        float bv = bias[ncol];
#pragma unroll
        for (int i = 0; i < 4; ++i)
          oO[(size_t)(rbase + i) * 1024 + ncol] = acc[m][n][i] + bv;
      }
    }
  } else {
    const int seg = bn >> 10;
    if (seg < 2) {
      f16* dst = seg == 0 ? oQ : oK;
#pragma unroll
      for (int m = 0; m < 4; ++m) {
        int rbase = bm + wr * 64 + m * 16 + ((lane >> 4) << 2);
#pragma unroll
        for (int n = 0; n < NF; ++n) {
          int ncol = (bn & 1023) + wc * 64 + n * 16 + (lane & 15);
          int h = ncol >> 6, dh = ncol & 63;
#pragma unroll
          for (int i = 0; i < 4; ++i) {
            int rr = rbase + i;
            int b = rr >> 11, s = rr & 2047;
            dst[(((size_t)(b * 16 + h) * 2048 + s) << 6) + dh] = (f16)acc[m][n][i];
          }
        }
      }
    } else {
      f16* T64 = smem;                   // [64][132] fits in 32KB union
      int b = bm >> 11, sbase = bm & 2047;
      int bnl = bn & 1023;
#pragma unroll
      for (int p = 0; p < 2; ++p) {
        if (wr == p) {
#pragma unroll
          for (int m = 0; m < 4; ++m)
#pragma unroll
            for (int n = 0; n < NF; ++n)
#pragma unroll
              for (int i = 0; i < 4; ++i) {
                int rl = m * 16 + ((lane >> 4) << 2) + i;
                int col = wc * 64 + n * 16 + (lane & 15);
                T64[rl * 132 + col] = (f16)acc[m][n][i];
              }
        }
        __syncthreads();
#pragma unroll
        for (int it = 0; it < 4; ++it) {
          int oc = it * 256 + tid;
          int ocol = oc >> 3;
          int och = oc & 7;
          f16x8 v;
#pragma unroll
          for (int j = 0; j < 8; ++j) v[j] = T64[(och * 8 + j) * 132 + ocol];
          int ncol = bnl + ocol;
          int h = ncol >> 6, dh = ncol & 63;
          *(f16x8*)(oV + ((size_t)((b * 16 + h) * 64 + dh) << 11) + sbase + p * 64 + och * 8) = v;
        }
        __syncthreads();
      }
    }
  }
}

// ---------------- causal flash attention ----------------
// grid (32, 32) = 1024 blocks (4/CU), 4 waves; ONE 64-row q-tile per block.
// qt swizzle balances per-CU load: dispatch id quarters alternate direction,
// so a CU's 4 resident blocks hold {bx, 31-bx, bx, 31-bx} = 66 iters/CU.
// Swapped QK^T (mfma(K,Q) -> S^T): lane-local softmax (R7-verified body).
__global__ __launch_bounds__(256, 2)
void attn_k(const f16* __restrict__ Q, const f16* __restrict__ Kg,
            const f16* __restrict__ Vt, f16* __restrict__ ctx) {
  __shared__ f16 sK[64 * 64];
  __shared__ f16 sV[64 * 64];
  __shared__ f16 sP[4][16 * 64];
  const int tid = threadIdx.x, lane = tid & 63, wid = tid >> 6;
  const int bh = blockIdx.y;
  const int b = bh >> 4, h = bh & 15;
  const int qt = ((bh >> 3) & 1) ? (31 - (int)blockIdx.x) : (int)blockIdx.x;
  const f16* Qb = Q + ((size_t)bh << 17);
  const f16* Kb = Kg + ((size_t)bh << 17);
  const f16* Vb = Vt + ((size_t)bh << 17);
  const float SC = 0.1803368801f;            // 0.125 * log2(e)

  const int qbase = qt * 64 + wid * 16;
  const int qg = qbase + (lane & 15);
  const int qmax_w = qbase + 15;

  const int qrow_a = qbase + (lane & 15);
  f16x8 qf[2];
  qf[0] = *(const f16x8*)(Qb + (size_t)qrow_a * 64 + ((lane >> 4) << 3));
  qf[1] = *(const f16x8*)(Qb + (size_t)qrow_a * 64 + 32 + ((lane >> 4) << 3));

  f32x4 acc[4] = {};
  float m_run = -INFINITY, l_run = 0.f;

  for (int kt = 0; kt <= qt; ++kt) {
#pragma unroll
    for (int p = 0; p < 2; ++p) {
      int c = p * 256 + tid;
      int row = c >> 3;
      int gc = (c & 7) ^ (row & 7);
      gload16(Kb + (size_t)(kt * 64 + row) * 64 + gc * 8, sK + c * 8);
      gload16(Vb + (size_t)row * 2048 + kt * 64 + gc * 8, sV + c * 8);
    }
    __syncthreads();

    // S^T = K Q^T : mfma(A=K_frag, B=Q_frag). Output: row=k_local, col=q.
    f32x4 sf[4];
#pragma unroll
    for (int kc = 0; kc < 4; ++kc) {
      if (kt * 64 + kc * 16 <= qmax_w) {
        f32x4 z = {};
#pragma unroll
        for (int ks = 0; ks < 2; ++ks) {
          int row = kc * 16 + (lane & 15);
          int j = (ks * 4 + (lane >> 4)) ^ (row & 7);
          f16x8 kf = *(const f16x8*)((const char*)sK + row * 128 + j * 16);
          z = __builtin_amdgcn_mfma_f32_16x16x32_f16(kf, qf[ks], z, 0, 0, 0);
        }
        sf[kc] = z;
      } else {
        sf[kc] = (f32x4){-1e30f, -1e30f, -1e30f, -1e30f};
      }
    }
#pragma unroll
    for (int kc = 0; kc < 4; ++kc) {
      if (kt * 64 + kc * 16 + 15 > qbase) {
#pragma unroll
        for (int i = 0; i < 4; ++i) {
          int kg = kt * 64 + kc * 16 + ((lane >> 4) << 2) + i;
          sf[kc][i] = (kg <= qg) ? sf[kc][i] * SC : -1e30f;
        }
      } else {
#pragma unroll
        for (int i = 0; i < 4; ++i) sf[kc][i] *= SC;
      }
    }
    float v01 = fmaxf(fmaxf(sf[0][0], sf[0][1]), fmaxf(sf[0][2], sf[0][3]));
    float v23 = fmaxf(fmaxf(sf[1][0], sf[1][1]), fmaxf(sf[1][2], sf[1][3]));
    float v45 = fmaxf(fmaxf(sf[2][0], sf[2][1]), fmaxf(sf[2][2], sf[2][3]));
    float v67 = fmaxf(fmaxf(sf[3][0], sf[3][1]), fmaxf(sf[3][2], sf[3][3]));
    float v = fmaxf(fmaxf(v01, v23), fmaxf(v45, v67));
    v = fmaxf(v, __shfl_xor(v, 16));
    v = fmaxf(v, __shfl_xor(v, 32));
    float mn = fmaxf(m_run, v);
    float scl = __builtin_amdgcn_exp2f(m_run - mn);
    m_run = mn;
    float ls = 0.f;
#pragma unroll
    for (int kc = 0; kc < 4; ++kc)
#pragma unroll
      for (int i = 0; i < 4; ++i) {
        float p = __builtin_amdgcn_exp2f(sf[kc][i] - mn);
        sf[kc][i] = p;
        ls += p;
      }
    ls += __shfl_xor(ls, 16);
    ls += __shfl_xor(ls, 32);
    l_run = l_run * scl + ls;
#pragma unroll
    for (int i = 0; i < 4; ++i) {
      float sb = __shfl(scl, ((lane >> 4) << 2) + i);
#pragma unroll
      for (int d = 0; d < 4; ++d) acc[d][i] *= sb;
    }
    char* Pw = (char*)(sP[wid]);
#pragma unroll
    for (int kc = 0; kc < 4; ++kc) {
      int kbase = kc * 16 + ((lane >> 4) << 2);
      int ch = kbase >> 3;
      f16x4 pv = { (f16)sf[kc][0], (f16)sf[kc][1], (f16)sf[kc][2], (f16)sf[kc][3] };
      *(f16x4*)(Pw + (lane & 15) * 128 + ((ch ^ (lane & 7)) << 4) + ((kbase & 7) << 1)) = pv;
    }
#pragma unroll
    for (int kk = 0; kk < 2; ++kk) {
      if (kt * 64 + kk * 32 <= qmax_w) {
        int prow = lane & 15;
        int pj = (kk * 4 + (lane >> 4)) ^ (prow & 7);
        f16x8 pa = *(const f16x8*)(Pw + prow * 128 + pj * 16);
#pragma unroll
        for (int d = 0; d < 4; ++d) {
          int vrow = d * 16 + (lane & 15);
          int vj = (kk * 4 + (lane >> 4)) ^ (vrow & 7);
          f16x8 vf = *(const f16x8*)((const char*)sV + vrow * 128 + vj * 16);
          acc[d] = __builtin_amdgcn_mfma_f32_16x16x32_f16(pa, vf, acc[d], 0, 0, 0);
        }
      }
    }
    __syncthreads();
  }
  // normalize + write ctx f16 [b][s][h*64+d]
#pragma unroll
  for (int i = 0; i < 4; ++i) {
    float lb = __shfl(l_run, ((lane >> 4) << 2) + i);
    float r = 1.f / lb;
    int s = qbase + ((lane >> 4) << 2) + i;
#pragma unroll
    for (int d = 0; d < 4; ++d) {
      float val = acc[d][i] * r;
      ctx[((size_t)(b * 2048 + s) << 10) + (h << 6) + (d << 4) + (lane & 15)] = (f16)val;
    }
  }
}

extern "C" void kernel_launch(void* const* d_in, const int* in_sizes, int n_in,
                              void* d_out, int out_size, void* d_ws, size_t ws_size,
                              hipStream_t stream) {
  const float* x  = (const float*)d_in[0];
  const float* Wq = (const float*)d_in[1];
  const float* Wk = (const float*)d_in[2];
  const float* Wv = (const float*)d_in[3];
  const float* Wo = (const float*)d_in[4];
  const float* bo = (const float*)d_in[5];
  char* ws = (char*)d_ws;
  f16* xb   = (f16*)(ws);
  f16* Wcat = (f16*)(ws + ((size_t)8  << 20));
  f16* Wot  = (f16*)(ws + ((size_t)14 << 20));
  f16* Qb   = (f16*)(ws + ((size_t)16 << 20));
  f16* Kb   = (f16*)(ws + ((size_t)24 << 20));
  f16* Vtb  = (f16*)(ws + ((size_t)32 << 20));
  f16* ctx  = (f16*)(ws + ((size_t)40 << 20));
  const size_t MM = (size_t)1024 * 1024;

  hipLaunchKernelGGL(cvt_x, dim3(4096), dim3(256), 0, stream, x, xb);
  hipLaunchKernelGGL(cvt_w, dim3(16, 16, 4), dim3(256), 0, stream,
                     Wq, Wk, Wv, Wo, Wcat, Wcat + MM, Wcat + 2 * MM, Wot);
  hipLaunchKernelGGL((gemm_k<0>), dim3(24, 32), dim3(256), 0, stream,
                     xb, Wcat, Qb, Kb, Vtb, nullptr, nullptr);
  hipLaunchKernelGGL(attn_k, dim3(32, 32), dim3(256), 0, stream, Qb, Kb, Vtb, ctx);
  hipLaunchKernelGGL((gemm_k<2>), dim3(16, 32), dim3(256), 0, stream,
                     ctx, Wot, nullptr, nullptr, nullptr, (float*)d_out, bo);
}